// Round 1
// baseline (1144.495 us; speedup 1.0000x reference)
//
#include <hip/hip_runtime.h>
#include <math.h>

#define BDIM 1024   // d_in
#define NP   130    // 2L
#define LL   65     // L = NUM_FREQ+1
#define DOUT 512

// ---------------------------------------------------------------------------
// K0: fill M'[130][1024] — column pair (2d, 2d+1) = (Re, Im) coefficients of
// A_d = sum_j a_j e^{i j theta_d},  theta_d = pi*(-1 + (2d+1)/512).
//   k <  65 (pr_j, j=k):    Re coeff =  cos(j*th), Im coeff = sin(j*th)
//   k >= 65 (pi_j, j=k-65): Re coeff = -sin(j*th), Im coeff = cos(j*th)
// ---------------------------------------------------------------------------
__global__ void fill_M_kernel(float* __restrict__ M) {
  int idx = blockIdx.x * 256 + threadIdx.x;
  if (idx >= NP * 1024) return;
  int k   = idx >> 10;
  int col = idx & 1023;
  int d   = col >> 1;
  int im  = col & 1;
  int j   = (k < LL) ? k : k - LL;
  double theta = M_PI * (-1.0 + (2.0 * (double)d + 1.0) / 512.0);
  double ph = (double)j * theta;
  double s = sin(ph), c = cos(ph);
  double v;
  if (k < LL) v = im ? s : c;
  else        v = im ? c : -s;
  M[idx] = (float)v;
}

// ---------------------------------------------------------------------------
// K1: GEMM1  P[B x 130] = X[B x 1024] @ W^T + b ; also R0[row] = sum_c P^2
// Tile: 64 rows x 144 cols (130 used), 256 threads = (tx 16) x (ty 16),
// each thread: 4 rows x 9 cols. K chunked by 32 through LDS.
// ---------------------------------------------------------------------------
#define KC1 32
__global__ __launch_bounds__(256) void gemm1_kernel(
    const float* __restrict__ X, const float* __restrict__ W,
    const float* __restrict__ bias, float* __restrict__ P,
    float* __restrict__ R0) {
  __shared__ float Xs[KC1][68];    // [kk][r], pad 68 keeps b128 reads aligned
  __shared__ float Ws[KC1][145];   // [kk][c], pad 145 breaks store conflicts
  __shared__ float Sred[64][17];
  const int tid = threadIdx.x;
  const int tx  = tid & 15;
  const int ty  = tid >> 4;
  const size_t rowbase = (size_t)blockIdx.x * 64;

  float acc[4][9];
#pragma unroll
  for (int r = 0; r < 4; r++)
#pragma unroll
    for (int j = 0; j < 9; j++) acc[r][j] = 0.f;

  for (int k0 = 0; k0 < BDIM; k0 += KC1) {
    __syncthreads();
    // stage X: 64 rows x 8 float4 (coalesced along k)
#pragma unroll
    for (int it = 0; it < 2; it++) {
      int lin = tid + it * 256;         // 0..511
      int r   = lin >> 3;
      int kq  = lin & 7;
      float4 v = *(const float4*)&X[(rowbase + r) * BDIM + k0 + kq * 4];
      Xs[kq * 4 + 0][r] = v.x; Xs[kq * 4 + 1][r] = v.y;
      Xs[kq * 4 + 2][r] = v.z; Xs[kq * 4 + 3][r] = v.w;
    }
    // stage W: 130 rows x 8 float4
    for (int lin = tid; lin < NP * 8; lin += 256) {
      int c  = lin >> 3;
      int kq = lin & 7;
      float4 v = *(const float4*)&W[(size_t)c * BDIM + k0 + kq * 4];
      Ws[kq * 4 + 0][c] = v.x; Ws[kq * 4 + 1][c] = v.y;
      Ws[kq * 4 + 2][c] = v.z; Ws[kq * 4 + 3][c] = v.w;
    }
    __syncthreads();
#pragma unroll 4
    for (int kk = 0; kk < KC1; kk++) {
      float4 xv = *(const float4*)&Xs[kk][ty * 4];
      float wv[9];
#pragma unroll
      for (int j = 0; j < 9; j++) wv[j] = Ws[kk][tx + 16 * j];
#pragma unroll
      for (int j = 0; j < 9; j++) {
        acc[0][j] = fmaf(xv.x, wv[j], acc[0][j]);
        acc[1][j] = fmaf(xv.y, wv[j], acc[1][j]);
        acc[2][j] = fmaf(xv.z, wv[j], acc[2][j]);
        acc[3][j] = fmaf(xv.w, wv[j], acc[3][j]);
      }
    }
  }
  // epilogue: add bias, write P, accumulate r0 = sum p^2 per row
  float s[4] = {0.f, 0.f, 0.f, 0.f};
#pragma unroll
  for (int j = 0; j < 9; j++) {
    int c = tx + 16 * j;
    if (c < NP) {
      float bj = bias[c];
#pragma unroll
      for (int rr = 0; rr < 4; rr++) {
        float pv = acc[rr][j] + bj;
        P[(rowbase + ty * 4 + rr) * NP + c] = pv;
        s[rr] = fmaf(pv, pv, s[rr]);
      }
    }
  }
#pragma unroll
  for (int rr = 0; rr < 4; rr++) Sred[ty * 4 + rr][tx] = s[rr];
  __syncthreads();
  if (tid < 64) {
    float t = 0.f;
#pragma unroll
    for (int i = 0; i < 16; i++) t += Sred[tid][i];
    R0[rowbase + tid] = t;
  }
}

// ---------------------------------------------------------------------------
// K2: GEMM2  A[B x 1024] = P[B x 130] @ M'[130 x 1024]; fused epilogue
//   out[row][d] = log((ReA^2 + ImA^2) / (512*r0) + 1e-5)
// Tile: 64 rows x 128 M-cols (= 64 output d's). 256 threads = (tx 64)x(ty 4);
// each thread owns 16 rows x 1 d (Re,Im adjacent). K padded 130->144, chunks
// of 16 staged in LDS.
// ---------------------------------------------------------------------------
__global__ __launch_bounds__(256) void gemm2_kernel(
    const float* __restrict__ P, const float* __restrict__ M,
    const float* __restrict__ R0, float* __restrict__ out) {
  __shared__ float Ps[64][148];   // [r][k], zero-padded k>=130
  __shared__ float Ms[16][128];
  const int tid = threadIdx.x;
  const int tx  = tid & 63;       // wave-uniform ty => Ps reads broadcast
  const int ty  = tid >> 6;
  const size_t rowbase = (size_t)blockIdx.y * 64;
  const int colbase = blockIdx.x * 128;

  // stage P tile once (64 rows x 148, zeros beyond k=129)
  for (int lin = tid; lin < 64 * 148; lin += 256) {
    int r = lin / 148;
    int k = lin - r * 148;
    float v = 0.f;
    if (k < NP) v = P[(rowbase + r) * NP + k];
    Ps[r][k] = v;
  }

  float acc[16][2];
#pragma unroll
  for (int rr = 0; rr < 16; rr++) { acc[rr][0] = 0.f; acc[rr][1] = 0.f; }

  for (int kc = 0; kc < 9; kc++) {
    int k0 = kc * 16;
    __syncthreads();   // also fences initial Ps staging on kc==0
#pragma unroll
    for (int it = 0; it < 8; it++) {
      int lin = tid + it * 256;   // 0..2047
      int kk = lin >> 7;
      int c  = lin & 127;
      int kg = k0 + kk;
      Ms[kk][c] = (kg < NP) ? M[(size_t)kg * 1024 + colbase + c] : 0.f;
    }
    __syncthreads();
#pragma unroll
    for (int kk = 0; kk < 16; kk += 4) {
      float2 mv[4];
#pragma unroll
      for (int q = 0; q < 4; q++) mv[q] = *(const float2*)&Ms[kk + q][2 * tx];
#pragma unroll
      for (int rr = 0; rr < 16; rr++) {
        float4 pv = *(const float4*)&Ps[ty * 16 + rr][k0 + kk];
        acc[rr][0] = fmaf(pv.x, mv[0].x, acc[rr][0]);
        acc[rr][1] = fmaf(pv.x, mv[0].y, acc[rr][1]);
        acc[rr][0] = fmaf(pv.y, mv[1].x, acc[rr][0]);
        acc[rr][1] = fmaf(pv.y, mv[1].y, acc[rr][1]);
        acc[rr][0] = fmaf(pv.z, mv[2].x, acc[rr][0]);
        acc[rr][1] = fmaf(pv.z, mv[2].y, acc[rr][1]);
        acc[rr][0] = fmaf(pv.w, mv[3].x, acc[rr][0]);
        acc[rr][1] = fmaf(pv.w, mv[3].y, acc[rr][1]);
      }
    }
  }

  const int dcol = blockIdx.x * 64 + tx;
#pragma unroll
  for (int rr = 0; rr < 16; rr++) {
    size_t row = rowbase + ty * 16 + rr;
    float r0v = R0[row];                       // wave-uniform
    float inv = 1.0f / (512.0f * r0v);
    float sq = acc[rr][0] * acc[rr][0] + acc[rr][1] * acc[rr][1];
    out[row * DOUT + dcol] = logf(fmaf(sq, inv, 1e-5f));
  }
}

// ---------------------------------------------------------------------------
extern "C" void kernel_launch(void* const* d_in, const int* in_sizes, int n_in,
                              void* d_out, int out_size, void* d_ws, size_t ws_size,
                              hipStream_t stream) {
  const float* X    = (const float*)d_in[0];   // [B x 1024]
  const float* W    = (const float*)d_in[1];   // [130 x 1024]
  const float* bias = (const float*)d_in[2];   // [130]
  float* out = (float*)d_out;                  // [B x 512]
  const int B = in_sizes[0] / BDIM;            // 65536

  // workspace layout (fp32): M'[130*1024] | R0[B] | P[B*130]  (~35 MB)
  float* ws_f = (float*)d_ws;
  float* M  = ws_f;
  float* R0 = ws_f + NP * 1024;
  float* P  = R0 + B;

  fill_M_kernel<<<(NP * 1024 + 255) / 256, 256, 0, stream>>>(M);
  gemm1_kernel<<<B / 64, 256, 0, stream>>>(X, W, bias, P, R0);
  gemm2_kernel<<<dim3(8, B / 64), 256, 0, stream>>>(P, M, R0, out);
}

// Round 2
// 522.580 us; speedup vs baseline: 2.1901x; 2.1901x over previous
//
#include <hip/hip_runtime.h>
#include <hip/hip_bf16.h>
#include <math.h>

#define BDIM 1024   // d_in
#define NP   130    // 2L
#define LL   65     // L
#define NPAD 144    // padded N for gemm1
#define KP2  160    // padded K for gemm2
#define DOUT 512

typedef __attribute__((ext_vector_type(4))) float f32x4;
typedef __attribute__((ext_vector_type(8))) __bf16 bf16x8;

// ---------------------------------------------------------------------------
// K0a: Wbf[144][1024] bf16, rows >=130 zeroed (ws is 0xAA-poisoned each call)
// ---------------------------------------------------------------------------
__global__ void fill_wbf(const float* __restrict__ W, __bf16* __restrict__ Wbf) {
  int idx = blockIdx.x * 256 + threadIdx.x;   // 144*1024
  int c = idx >> 10, k = idx & 1023;
  float v = (c < NP) ? W[c * BDIM + k] : 0.f;
  Wbf[idx] = (__bf16)v;
}

// ---------------------------------------------------------------------------
// K0b: Mt[1024][160] bf16 — TRANSPOSED M' so gemm2 B-frags are k-contiguous.
// Mt[col][k]: col=2d+im; k<65: j=k, (Re:cos, Im:sin); k>=65: j=k-65,
// (Re:-sin, Im:cos). k in [130,160) zero.
// ---------------------------------------------------------------------------
__global__ void fill_mt(__bf16* __restrict__ Mt) {
  int idx = blockIdx.x * 256 + threadIdx.x;   // 1024*160
  int col = idx / KP2, k = idx - col * KP2;
  int d = col >> 1, im = col & 1;
  float v = 0.f;
  if (k < NP) {
    int j = (k < LL) ? k : k - LL;
    double theta = M_PI * (-1.0 + (2.0 * (double)d + 1.0) / 512.0);
    double ph = (double)j * theta;
    double s = sin(ph), c = cos(ph);
    v = (float)((k < LL) ? (im ? s : c) : (im ? c : -s));
  }
  Mt[idx] = (__bf16)v;
}

// ---------------------------------------------------------------------------
// K1: MFMA GEMM1  P[row][c] = bf16( X[row]@W[c] + b[c] ),
//     R0[row] = 1/(512*sum_c p^2).  No LDS: A-frags direct from global fp32
//     (cvt in-reg), B-frags direct bf16 from Wbf.
// Block = 4 waves x 32 rows = 128 rows. Wave: 2 row-tiles x 9 col-tiles.
// ---------------------------------------------------------------------------
__global__ __launch_bounds__(256) void gemm1(
    const float* __restrict__ X, const __bf16* __restrict__ Wbf,
    const float* __restrict__ bias, __bf16* __restrict__ P,
    float* __restrict__ R0) {
  const int tid  = threadIdx.x;
  const int w    = tid >> 6;
  const int lane = tid & 63;
  const int l15  = lane & 15;
  const int quad = lane >> 4;
  const long rowbase = (long)blockIdx.x * 128 + w * 32;

  f32x4 acc[2][9];
#pragma unroll
  for (int rt = 0; rt < 2; rt++)
#pragma unroll
    for (int j = 0; j < 9; j++) acc[rt][j] = (f32x4){0.f, 0.f, 0.f, 0.f};

  const float*  xptr = X   + (rowbase + l15) * BDIM + quad * 8;
  const __bf16* wptr = Wbf + (long)l15 * BDIM + quad * 8;

  for (int k0 = 0; k0 < BDIM; k0 += 32) {
    bf16x8 a[2];
#pragma unroll
    for (int rt = 0; rt < 2; rt++) {
      f32x4 x0 = *(const f32x4*)(xptr + (long)rt * 16 * BDIM + k0);
      f32x4 x1 = *(const f32x4*)(xptr + (long)rt * 16 * BDIM + k0 + 4);
      bf16x8 af;
      af[0] = (__bf16)x0[0]; af[1] = (__bf16)x0[1];
      af[2] = (__bf16)x0[2]; af[3] = (__bf16)x0[3];
      af[4] = (__bf16)x1[0]; af[5] = (__bf16)x1[1];
      af[6] = (__bf16)x1[2]; af[7] = (__bf16)x1[3];
      a[rt] = af;
    }
#pragma unroll
    for (int j = 0; j < 9; j++) {
      bf16x8 b = *(const bf16x8*)(wptr + (long)j * 16 * BDIM + k0);
      acc[0][j] = __builtin_amdgcn_mfma_f32_16x16x32_bf16(a[0], b, acc[0][j], 0, 0, 0);
      acc[1][j] = __builtin_amdgcn_mfma_f32_16x16x32_bf16(a[1], b, acc[1][j], 0, 0, 0);
    }
  }

  // epilogue: bias, P store (bf16, zero-padded), r0 reduction
  float s[2][4];
#pragma unroll
  for (int rt = 0; rt < 2; rt++)
#pragma unroll
    for (int reg = 0; reg < 4; reg++) s[rt][reg] = 0.f;

#pragma unroll
  for (int j = 0; j < 9; j++) {
    int c = j * 16 + l15;
    float bj = (c < NP) ? bias[c] : 0.f;
#pragma unroll
    for (int rt = 0; rt < 2; rt++) {
#pragma unroll
      for (int reg = 0; reg < 4; reg++) {
        long row = rowbase + rt * 16 + quad * 4 + reg;
        float pv = acc[rt][j][reg] + bj;
        if (c >= NP) pv = 0.f;                 // zero the 130..143 pad
        P[row * KP2 + c] = (__bf16)pv;
        s[rt][reg] = fmaf(pv, pv, s[rt][reg]);
      }
    }
  }
  // zero pad cols 144..159 (all lanes cover 4 quad-rows x 16 cols per (rt,reg))
#pragma unroll
  for (int rt = 0; rt < 2; rt++)
#pragma unroll
    for (int reg = 0; reg < 4; reg++) {
      long row = rowbase + rt * 16 + quad * 4 + reg;
      P[row * KP2 + NPAD + l15] = (__bf16)0.f;
    }
  // reduce sum p^2 across the 16-lane col groups; store reciprocal factor
#pragma unroll
  for (int rt = 0; rt < 2; rt++)
#pragma unroll
    for (int reg = 0; reg < 4; reg++) {
      float v = s[rt][reg];
      v += __shfl_xor(v, 1);
      v += __shfl_xor(v, 2);
      v += __shfl_xor(v, 4);
      v += __shfl_xor(v, 8);
      if (l15 == 0) {
        long row = rowbase + rt * 16 + quad * 4 + reg;
        R0[row] = 1.0f / (512.0f * v);
      }
    }
}

// ---------------------------------------------------------------------------
// K2: MFMA GEMM2  A[row][acol] = P[row][0:160] @ Mt[acol][0:160]^T, fused
//     out[row][d] = __logf(|A|^2 * R0[row] + 1e-5), d = acol>>1.
// Block = 128 rows x 128 acols, 2x2 waves of 64x64. K=160 (5 steps).
// Grid x = row-blocks (fastest) so the Mt tile stays L2-hot per y.
// ---------------------------------------------------------------------------
__global__ __launch_bounds__(256) void gemm2(
    const __bf16* __restrict__ P, const __bf16* __restrict__ Mt,
    const float* __restrict__ R0, float* __restrict__ out) {
  const int tid  = threadIdx.x;
  const int w    = tid >> 6;
  const int wr   = w >> 1, wc = w & 1;
  const int lane = tid & 63;
  const int l15  = lane & 15;
  const int quad = lane >> 4;
  const long rowbase = (long)blockIdx.x * 128 + wr * 64;
  const int  colbase = blockIdx.y * 128 + wc * 64;

  f32x4 acc[4][4];   // [rtile][ctile]
#pragma unroll
  for (int rt = 0; rt < 4; rt++)
#pragma unroll
    for (int ct = 0; ct < 4; ct++) acc[rt][ct] = (f32x4){0.f, 0.f, 0.f, 0.f};

  const __bf16* pptr = P  + (rowbase + l15) * KP2 + quad * 8;
  const __bf16* mptr = Mt + (long)(colbase + l15) * KP2 + quad * 8;

#pragma unroll
  for (int k0 = 0; k0 < KP2; k0 += 32) {
    bf16x8 a[4], b[4];
#pragma unroll
    for (int t = 0; t < 4; t++) a[t] = *(const bf16x8*)(pptr + (long)t * 16 * KP2 + k0);
#pragma unroll
    for (int t = 0; t < 4; t++) b[t] = *(const bf16x8*)(mptr + (long)t * 16 * KP2 + k0);
#pragma unroll
    for (int rt = 0; rt < 4; rt++)
#pragma unroll
      for (int ct = 0; ct < 4; ct++)
        acc[rt][ct] = __builtin_amdgcn_mfma_f32_16x16x32_bf16(a[rt], b[ct], acc[rt][ct], 0, 0, 0);
  }

  // epilogue: |A|^2 via lane-pair shfl, parity-split log + store
  const int par = lane & 1;
#pragma unroll
  for (int rt = 0; rt < 4; rt++) {
#pragma unroll
    for (int ct = 0; ct < 4; ct++) {
      const int d = (colbase >> 1) + ct * 8 + (l15 >> 1);
      float t[4];
#pragma unroll
      for (int reg = 0; reg < 4; reg++) {
        float v = acc[rt][ct][reg];
        t[reg] = v * v;
        t[reg] += __shfl_xor(t[reg], 1);    // Re^2 + Im^2, both lanes of pair
      }
#pragma unroll
      for (int q = 0; q < 2; q++) {
        int reg = par * 2 + q;              // even lane: regs 0,1; odd: 2,3
        long row = rowbase + rt * 16 + quad * 4 + reg;
        float inv = R0[row];                // already 1/(512*r0)
        out[row * DOUT + d] = __logf(fmaf(t[reg], inv, 1e-5f));
      }
    }
  }
}

// ---------------------------------------------------------------------------
extern "C" void kernel_launch(void* const* d_in, const int* in_sizes, int n_in,
                              void* d_out, int out_size, void* d_ws, size_t ws_size,
                              hipStream_t stream) {
  const float* X    = (const float*)d_in[0];   // [B x 1024]
  const float* W    = (const float*)d_in[1];   // [130 x 1024]
  const float* bias = (const float*)d_in[2];   // [130]
  float* out = (float*)d_out;                  // [B x 512]
  const int B = in_sizes[0] / BDIM;            // 65536

  // ws layout: P[B*160] bf16 | Wbf[144*1024] bf16 | Mt[1024*160] bf16 | R0[B] f32
  char* ws = (char*)d_ws;
  __bf16* P   = (__bf16*)ws;                         ws += (size_t)B * KP2 * 2;
  __bf16* Wbf = (__bf16*)ws;                         ws += (size_t)NPAD * BDIM * 2;
  __bf16* Mt  = (__bf16*)ws;                         ws += (size_t)BDIM * KP2 * 2;
  float*  R0  = (float*)ws;

  fill_wbf<<<(NPAD * BDIM) / 256, 256, 0, stream>>>(W, Wbf);
  fill_mt<<<(BDIM * KP2) / 256, 256, 0, stream>>>(Mt);
  gemm1<<<B / 128, 256, 0, stream>>>(X, Wbf, bias, P, R0);
  gemm2<<<dim3(B / 128, 8), 256, 0, stream>>>(P, Mt, R0, out);
}